// Round 12
// baseline (573.524 us; speedup 1.0000x reference)
//
#include <hip/hip_runtime.h>
#include <hip/hip_bf16.h>

// Problem constants
#define Tt 4096   // B*L tokens
#define Dd 1024   // model dim
#define Ee 8      // experts
#define Kk 2      // top-k
#define Ff 4096   // DFF

using f32x4  = __attribute__((ext_vector_type(4))) float;
using bf16x8 = __attribute__((ext_vector_type(8))) short;

__device__ __forceinline__ unsigned short f2bf(float f) {
    union { float fp; unsigned int u; } v; v.fp = f;
    unsigned int u = v.u;
    return (unsigned short)((u + 0x7FFFu + ((u >> 16) & 1u)) >> 16);  // RNE
}

__device__ __forceinline__ void gl16(const void* g, void* l) {
    __builtin_amdgcn_global_load_lds(
        (const __attribute__((address_space(1))) void*)g,
        (__attribute__((address_space(3))) void*)l, 16, 0, 0);
}

// ---------------- Router (+ x->bf16): logits fp64, softmax, top-2, renorm ----------------
__global__ void router_kernel(const float* __restrict__ x, const float* __restrict__ Wr,
                              int* __restrict__ ids, float* __restrict__ wts,
                              int* __restrict__ counts, unsigned short* __restrict__ xb) {
    const int t = blockIdx.x;
    const int lane = threadIdx.x;  // 64
    const float* xr = x + (size_t)t * Dd + lane * 16;
    float xv[16];
#pragma unroll
    for (int i = 0; i < 4; ++i) *(float4*)(xv + 4 * i) = *(const float4*)(xr + 4 * i);
    uint4 o0, o1;
    o0.x = (unsigned)f2bf(xv[0])  | ((unsigned)f2bf(xv[1])  << 16);
    o0.y = (unsigned)f2bf(xv[2])  | ((unsigned)f2bf(xv[3])  << 16);
    o0.z = (unsigned)f2bf(xv[4])  | ((unsigned)f2bf(xv[5])  << 16);
    o0.w = (unsigned)f2bf(xv[6])  | ((unsigned)f2bf(xv[7])  << 16);
    o1.x = (unsigned)f2bf(xv[8])  | ((unsigned)f2bf(xv[9])  << 16);
    o1.y = (unsigned)f2bf(xv[10]) | ((unsigned)f2bf(xv[11]) << 16);
    o1.z = (unsigned)f2bf(xv[12]) | ((unsigned)f2bf(xv[13]) << 16);
    o1.w = (unsigned)f2bf(xv[14]) | ((unsigned)f2bf(xv[15]) << 16);
    unsigned short* xo = xb + (size_t)t * Dd + lane * 16;
    *(uint4*)(xo) = o0;
    *(uint4*)(xo + 8) = o1;

    double dot[Ee];
#pragma unroll
    for (int e = 0; e < Ee; ++e) {
        const float* wr = Wr + e * Dd + lane * 16;
        double s = 0.0;
#pragma unroll
        for (int i = 0; i < 16; ++i) s += (double)xv[i] * (double)wr[i];
        dot[e] = s;
    }
#pragma unroll
    for (int off = 32; off >= 1; off >>= 1) {
#pragma unroll
        for (int e = 0; e < Ee; ++e) dot[e] += __shfl_xor(dot[e], off, 64);
    }
    if (lane == 0) {
        float lg[Ee];
#pragma unroll
        for (int e = 0; e < Ee; ++e) lg[e] = (float)dot[e];
        float m = lg[0];
        for (int e = 1; e < Ee; ++e) m = fmaxf(m, lg[e]);
        float ex[Ee]; float sum = 0.f;
        for (int e = 0; e < Ee; ++e) { ex[e] = expf(lg[e] - m); sum += ex[e]; }
        float s0 = -1.f, s1 = -1.f; int i0 = 0, i1 = 0;
        for (int e = 0; e < Ee; ++e) {
            float s = ex[e];
            if (s > s0)      { s1 = s0; i1 = i0; s0 = s; i0 = e; }
            else if (s > s1) { s1 = s; i1 = e; }
        }
        float inv = 1.f / sum;
        float sc0 = s0 * inv, sc1 = s1 * inv;
        float den = sc0 + sc1 + 1.1920929e-7f;
        ids[2 * t] = i0; ids[2 * t + 1] = i1;
        wts[2 * t] = sc0 / den; wts[2 * t + 1] = sc1 / den;
        atomicAdd(&counts[i0], 1);
        atomicAdd(&counts[i1], 1);
    }
}

// ---------------- Wg/Wu -> interleaved bf16 Wgu ----------------
__global__ void cvt_wgu(const float* __restrict__ Wg, const float* __restrict__ Wu,
                        unsigned short* __restrict__ Wgu) {
    size_t tid = (size_t)blockIdx.x * blockDim.x + threadIdx.x;
    size_t row = tid >> 7;          // 128 threads per 1024-elem row
    int dc  = (int)(tid & 127);
    int e   = (int)(row >> 13);     // 8192 rows/expert
    int j   = (int)(row & 8191);
    int fg = j >> 5, s = (j >> 4) & 1, fi = j & 15;
    int f  = fg * 16 + fi;
    const float* src = (s ? Wu : Wg) + ((size_t)e * Ff + f) * Dd + dc * 8;
    float4 a = *(const float4*)(src);
    float4 b = *(const float4*)(src + 4);
    uint4 o;
    o.x = (unsigned)f2bf(a.x) | ((unsigned)f2bf(a.y) << 16);
    o.y = (unsigned)f2bf(a.z) | ((unsigned)f2bf(a.w) << 16);
    o.z = (unsigned)f2bf(b.x) | ((unsigned)f2bf(b.y) << 16);
    o.w = (unsigned)f2bf(b.z) | ((unsigned)f2bf(b.w) << 16);
    *(uint4*)(Wgu + row * Dd + dc * 8) = o;
}

// ---------------- counts -> offsets + cursors ----------------
__global__ void scan_kernel(const int* __restrict__ counts, int* __restrict__ cursor,
                            int* __restrict__ eoff) {
    if (threadIdx.x == 0) {
        int acc = 0;
        for (int e = 0; e < Ee; ++e) { eoff[e] = acc; cursor[e] = acc; acc += counts[e]; }
        eoff[Ee] = acc;
    }
}

// ---------------- scatter: rows[pos] = 2*t+k ----------------
__global__ void scatter_kernel(const int* __restrict__ ids,
                               int* __restrict__ cursor, int* __restrict__ rows) {
    int t = blockIdx.x * blockDim.x + threadIdx.x;
    if (t >= Tt) return;
#pragma unroll
    for (int k = 0; k < Kk; ++k) {
        int e = ids[2 * t + k];
        int pos = atomicAdd(&cursor[e], 1);
        rows[pos] = 2 * t + k;
    }
}

// =================== MTx256 BK=64 8-wave 4-phase counted-vmcnt GEMM body ===================
// Schedule structure identical to round-6 (verified deterministic). MT templated:
// G1: MT=256 (4 A-issues/tile, vmcnt(4)); G2: MT=320 (5 A-issues/tile, vmcnt(5)).
// G2 MT=320 -> active blocks = 4n x 2sK x ceil(ne/320)=4 x 8e = 256 = exactly 1/CU
// (kills the ~280-block quantization cliff that made g2 ~2x its block time).
// LDS layout: A bufs at 0 / ABUFU; B bufs at 2*ABUFU / +16384 (ushort units).
// Ledger: tile-end vmcnt(AISS) leaves exactly A(t+2) in flight, drains B(t+1);
// tail vmcnt(0) once t+2>=NT (r3 lesson). lgkm drains per r6.

#define MFMA_BF16(a, b, c) __builtin_amdgcn_mfma_f32_16x16x32_bf16(a, b, c, 0, 0, 0)

template<bool G2>
__device__ __forceinline__ void gemm_body(unsigned short* Ls,
                                          const unsigned short* __restrict__ Abase,
                                          const unsigned short* __restrict__ Bbase,
                                          const int* __restrict__ eoff,
                                          const int* __restrict__ rows,
                                          unsigned short* __restrict__ H,
                                          float* __restrict__ partial) {
    constexpr int KLEN  = G2 ? Ff : Dd;            // physical A/B row length
    constexpr int NT    = (G2 ? 2048 : 1024) / 64; // K-tiles this block processes
    constexpr int MT    = G2 ? 320 : 256;          // M tile
    constexpr int MFR   = MT / 32;                 // m-frags per wave (10 / 8)
    constexpr int AISS  = MT / 64;                 // A gl16 issues per tile (5 / 4)
    constexpr int ABUFU = MT * 64;                 // ushorts per A buffer
    constexpr int BBASE = 2 * ABUFU;               // B region offset (ushorts)
    const int e   = blockIdx.z;
    const int off = eoff[e];
    const int ne  = eoff[e + 1] - off;
    const int by  = blockIdx.y;
    const int my  = G2 ? (by >> 1) : by;
    const int sK  = G2 ? (by & 1) : 0;
    const int koff = sK * 2048;
    const int m0  = my * MT;
    if (m0 >= ne) return;
    const int n0  = blockIdx.x * 256;

    const int tid  = threadIdx.x;
    const int lane = tid & 63;
    const int w    = tid >> 6;        // wave 0..7
    const int wr   = w >> 2;          // 0..1 (M half)
    const int wc   = w & 3;           // 0..3 (N quarter)
    const int lr   = lane & 15;
    const int lc   = lane >> 4;       // 0..3

    const int sr = lane >> 3;                 // 0..7
    const int cA = (lane & 7) ^ sr;           // pre-swizzled source chunk
    int asrc[AISS];
#pragma unroll
    for (int j = 0; j < AISS; ++j) {
        int rr = m0 + j * 64 + w * 8 + sr;
        if (rr > ne - 1) rr = ne - 1;
        asrc[j] = (G2 ? (off + rr) : (rows[off + rr] >> 1)) * KLEN + cA * 8;
    }
    const unsigned short* Bp = Bbase + (size_t)e * (G2 ? (size_t)Dd * Ff : (size_t)8192 * Dd);
    int bsrc[4];
#pragma unroll
    for (int qq = 0; qq < 4; ++qq) {
        int rN = n0 + qq * 64 + w * 8 + sr;
        bsrc[qq] = rN * KLEN + cA * 8;
    }

    auto STAGE_A = [&](int T, int half) {
        const int bo_ = (T & 1) * ABUFU; const int kt_ = koff + T * 64;
        if (half == 0) {
            gl16(Abase + asrc[0] + kt_, Ls + bo_ + 0 * 4096 + w * 512);
            gl16(Abase + asrc[1] + kt_, Ls + bo_ + 1 * 4096 + w * 512);
            if constexpr (G2) gl16(Abase + asrc[2] + kt_, Ls + bo_ + 2 * 4096 + w * 512);
        } else {
            if constexpr (G2) {
                gl16(Abase + asrc[3] + kt_, Ls + bo_ + 3 * 4096 + w * 512);
                gl16(Abase + asrc[4] + kt_, Ls + bo_ + 4 * 4096 + w * 512);
            } else {
                gl16(Abase + asrc[2] + kt_, Ls + bo_ + 2 * 4096 + w * 512);
                gl16(Abase + asrc[3] + kt_, Ls + bo_ + 3 * 4096 + w * 512);
            }
        }
    };
    auto STAGE_B = [&](int T, int Hh) {
        const int bo_ = BBASE + (T & 1) * 16384; const int kt_ = koff + T * 64;
        gl16(Bp + bsrc[2 * Hh]     + kt_, Ls + bo_ + (2 * Hh)     * 4096 + w * 512);
        gl16(Bp + bsrc[2 * Hh + 1] + kt_, Ls + bo_ + (2 * Hh + 1) * 4096 + w * 512);
    };

#define WAIT_STEADY() do { if constexpr (G2) { asm volatile("s_waitcnt vmcnt(5)" ::: "memory"); } \
                           else              { asm volatile("s_waitcnt vmcnt(4)" ::: "memory"); } } while (0)

    const int ccx0 = ((0 * 4 + lc) ^ (lr & 7)) * 8;
    const int ccx1 = ((1 * 4 + lc) ^ (lr & 7)) * 8;
    const int aB = (wr * (MT / 2)) * 64 + lr * 64;     // + (t&1)*ABUFU + m*1024 + ccx
    const int bB = BBASE + wc * 4096 + lr * 64;        // + (t&1)*16384 + n*1024 + ccx

    f32x4 acc[MFR][4];
#pragma unroll
    for (int m = 0; m < MFR; ++m)
#pragma unroll
        for (int n = 0; n < 4; ++n) acc[m][n] = (f32x4){0.f, 0.f, 0.f, 0.f};

    // --- prologue: tile0 fully + tile1 A; wait leaves A(1) in flight ---
    STAGE_A(0, 0); STAGE_A(0, 1); STAGE_B(0, 0); STAGE_B(0, 1);
    STAGE_A(1, 0); STAGE_A(1, 1);
    WAIT_STEADY();
    __builtin_amdgcn_sched_barrier(0);
    __builtin_amdgcn_s_barrier();

    bf16x8 a0[MFR], a1[MFR], b0[4], b1[4];

    for (int t = 0; t < NT; ++t) {
        const int abo = (t & 1) * ABUFU;
        const int bbo = (t & 1) * 16384;
        // ---- P1: read a_kk0 + b_kk0; stage (t+1).B0 ----
#pragma unroll
        for (int m = 0; m < MFR; ++m) a0[m] = *(const bf16x8*)(Ls + abo + aB + m * 1024 + ccx0);
#pragma unroll
        for (int n = 0; n < 4; ++n) b0[n] = *(const bf16x8*)(Ls + bbo + bB + n * 1024 + ccx0);
        if (t + 1 < NT) STAGE_B(t + 1, 0);
        __builtin_amdgcn_s_barrier();
        asm volatile("s_waitcnt lgkmcnt(0)" ::: "memory");
        __builtin_amdgcn_sched_barrier(0);
        __builtin_amdgcn_s_setprio(1);
#pragma unroll
        for (int m = 0; m < MFR; ++m) {
            acc[m][0] = MFMA_BF16(a0[m], b0[0], acc[m][0]);
            acc[m][1] = MFMA_BF16(a0[m], b0[1], acc[m][1]);
        }
        __builtin_amdgcn_s_setprio(0);
        __builtin_amdgcn_s_barrier();
        // ---- P2: read a_kk1; stage (t+1).B1; MFMA kk0 nh1; REQUIRED lgkm-drain ----
#pragma unroll
        for (int m = 0; m < MFR; ++m) a1[m] = *(const bf16x8*)(Ls + abo + aB + m * 1024 + ccx1);
        if (t + 1 < NT) STAGE_B(t + 1, 1);
        __builtin_amdgcn_s_barrier();
        __builtin_amdgcn_s_setprio(1);
#pragma unroll
        for (int m = 0; m < MFR; ++m) {
            acc[m][2] = MFMA_BF16(a0[m], b0[2], acc[m][2]);
            acc[m][3] = MFMA_BF16(a0[m], b0[3], acc[m][3]);
        }
        __builtin_amdgcn_s_setprio(0);
        asm volatile("s_waitcnt lgkmcnt(0)" ::: "memory");
        __builtin_amdgcn_sched_barrier(0);
        __builtin_amdgcn_s_barrier();
        // ---- P3: read b_kk1; stage (t+2).A0; MFMA kk1 nh0 ----
#pragma unroll
        for (int n = 0; n < 4; ++n) b1[n] = *(const bf16x8*)(Ls + bbo + bB + n * 1024 + ccx1);
        if (t + 2 < NT) STAGE_A(t + 2, 0);
        __builtin_amdgcn_s_barrier();
        asm volatile("s_waitcnt lgkmcnt(0)" ::: "memory");
        __builtin_amdgcn_sched_barrier(0);
        __builtin_amdgcn_s_setprio(1);
#pragma unroll
        for (int m = 0; m < MFR; ++m) {
            acc[m][0] = MFMA_BF16(a1[m], b1[0], acc[m][0]);
            acc[m][1] = MFMA_BF16(a1[m], b1[1], acc[m][1]);
        }
        __builtin_amdgcn_s_setprio(0);
        __builtin_amdgcn_s_barrier();
        // ---- P4: stage (t+2).A1; MFMA kk1 nh1; counted vmcnt (tail-corrected) ----
        if (t + 2 < NT) STAGE_A(t + 2, 1);
        __builtin_amdgcn_s_setprio(1);
#pragma unroll
        for (int m = 0; m < MFR; ++m) {
            acc[m][2] = MFMA_BF16(a1[m], b1[2], acc[m][2]);
            acc[m][3] = MFMA_BF16(a1[m], b1[3], acc[m][3]);
        }
        __builtin_amdgcn_s_setprio(0);
        if (t + 2 < NT) { WAIT_STEADY(); }
        else            { asm volatile("s_waitcnt vmcnt(0)" ::: "memory"); }
        __builtin_amdgcn_sched_barrier(0);
        __builtin_amdgcn_s_barrier();
    }

    if constexpr (!G2) {
        const int fg16 = ((n0 + wc * 64) >> 5) * 16 + lr;
#pragma unroll
        for (int m = 0; m < MFR; ++m) {
            const int itok = m0 + wr * (MT / 2) + m * 16 + lc * 4;
#pragma unroll
            for (int r = 0; r < 4; ++r) {
                const int i = itok + r;
                if (i < ne) {
                    unsigned short* hp = H + (size_t)(off + i) * Ff;
#pragma unroll
                    for (int np = 0; np < 2; ++np) {
                        const float g = acc[m][2 * np][r];
                        const float u = acc[m][2 * np + 1][r];
                        hp[fg16 + np * 16] = f2bf(fmaxf(g, 0.f) * u);
                    }
                }
            }
        }
    } else {
        const int dbase = n0 + wc * 64;
#pragma unroll
        for (int m = 0; m < MFR; ++m) {
            const int ib = m0 + wr * (MT / 2) + m * 16 + lc * 4;
#pragma unroll
            for (int r = 0; r < 4; ++r) {
                const int i = ib + r;
                if (i < ne) {
                    const int tr = rows[off + i];  // 2t+k, token-determined target
                    float* op = partial + ((size_t)sK * 8192 + tr) * Dd + dbase + lr;
#pragma unroll
                    for (int n = 0; n < 4; ++n) op[n * 16] = acc[m][n][r];
                }
            }
        }
    }
#undef WAIT_STEADY
}

// g1: gemm1 + folded Wd fp32->bf16 conversion tail (every block, incl. early-exit ones)
__global__ __launch_bounds__(512, 1)
void g1_moe(const unsigned short* __restrict__ xb, const unsigned short* __restrict__ Wgu,
            const int* __restrict__ eoff, const int* __restrict__ rows,
            unsigned short* __restrict__ H,
            const float* __restrict__ Wd, unsigned short* __restrict__ Wdb) {
    __shared__ __align__(16) unsigned short Ls[65536];  // 128 KiB (2x16K A + 2x16K B ushorts)
    gemm_body<false>(Ls, xb, Wgu, eoff, rows, H, nullptr);
    // Wd convert slice: 4096 blocks x 8192 elems = 33.55M
    const int fb = blockIdx.x + gridDim.x * (blockIdx.y + gridDim.y * blockIdx.z);
    const size_t base = (size_t)fb * 8192;
#pragma unroll
    for (int it = 0; it < 2; ++it) {
        const size_t i = base + (size_t)it * 4096 + threadIdx.x * 8;
        float4 a = *(const float4*)(Wd + i);
        float4 b = *(const float4*)(Wd + i + 4);
        uint4 o;
        o.x = (unsigned)f2bf(a.x) | ((unsigned)f2bf(a.y) << 16);
        o.y = (unsigned)f2bf(a.z) | ((unsigned)f2bf(a.w) << 16);
        o.z = (unsigned)f2bf(b.x) | ((unsigned)f2bf(b.y) << 16);
        o.w = (unsigned)f2bf(b.z) | ((unsigned)f2bf(b.w) << 16);
        *(uint4*)(Wdb + i) = o;
    }
}

__global__ __launch_bounds__(512, 1)
void g2_moe(const unsigned short* __restrict__ H, const unsigned short* __restrict__ Wdb,
            const int* __restrict__ eoff, const int* __restrict__ rows,
            float* __restrict__ partial) {
    __shared__ __align__(16) unsigned short Ls[2 * (320 * 64) + 2 * 16384];  // 144 KiB
    gemm_body<true>(Ls, H, Wdb, eoff, rows, nullptr, partial);
}

// ---------------- deterministic combine: out = w0*(P0a+P1a) + w1*(P0b+P1b) ----------------
__global__ void reduce_kernel(const float* __restrict__ P, const float* __restrict__ wts,
                              float* __restrict__ out) {
    const size_t idx = (size_t)blockIdx.x * blockDim.x + threadIdx.x;
    const size_t t  = idx >> 8;
    const int   dq  = (int)(idx & 255);
    const float w0 = wts[2 * t], w1 = wts[2 * t + 1];
    const float4* p00 = (const float4*)(P + (2 * t)        * Dd) + dq;
    const float4* p01 = (const float4*)(P + (2 * t + 1)    * Dd) + dq;
    const float4* p10 = (const float4*)(P + ((size_t)8192 + 2 * t)     * Dd) + dq;
    const float4* p11 = (const float4*)(P + ((size_t)8192 + 2 * t + 1) * Dd) + dq;
    float4 a = *p00, b = *p01, c = *p10, d = *p11;
    float4 o;
    o.x = w0 * (a.x + c.x) + w1 * (b.x + d.x);
    o.y = w0 * (a.y + c.y) + w1 * (b.y + d.y);
    o.z = w0 * (a.z + c.z) + w1 * (b.z + d.z);
    o.w = w0 * (a.w + c.w) + w1 * (b.w + d.w);
    ((float4*)(out + t * Dd))[dq] = o;
}

extern "C" void kernel_launch(void* const* d_in, const int* in_sizes, int n_in,
                              void* d_out, int out_size, void* d_ws, size_t ws_size,
                              hipStream_t stream) {
    const float* x  = (const float*)d_in[0];
    const float* Wr = (const float*)d_in[1];
    const float* Wg = (const float*)d_in[2];
    const float* Wu = (const float*)d_in[3];
    const float* Wd = (const float*)d_in[4];
    float* out = (float*)d_out;
    char* ws = (char*)d_ws;

    const size_t WELEM    = (size_t)Ee * Ff * Dd;            // 33.55M
    const size_t OFF_IDS  = 256;
    const size_t OFF_WTS  = OFF_IDS  + (size_t)Tt * 2 * 4;
    const size_t OFF_ROWS = OFF_WTS  + (size_t)Tt * 2 * 4;
    const size_t OFF_ROWW = OFF_ROWS + (size_t)Tt * Kk * 4;
    const size_t OFF_XB   = OFF_ROWW + (size_t)Tt * Kk * 4;
    const size_t OFF_H    = OFF_XB   + (size_t)Tt * Dd * 2;
    const size_t OFF_WGU  = OFF_H    + (size_t)Tt * Kk * Ff * 2;
    const size_t OFF_WD   = OFF_WGU  + WELEM * 2 * 2;        // Wgu = 2*WELEM bf16
    const size_t NEED     = OFF_WD   + WELEM * 2;            // ~264 MiB
    if (ws_size < NEED) return;

    int* counts = (int*)ws;
    int* cursor = (int*)(ws + 32);
    int* eoff   = (int*)(ws + 64);
    int* ids    = (int*)(ws + OFF_IDS);
    float* wts  = (float*)(ws + OFF_WTS);
    int* rows   = (int*)(ws + OFF_ROWS);
    unsigned short* xb  = (unsigned short*)(ws + OFF_XB);
    unsigned short* H   = (unsigned short*)(ws + OFF_H);
    unsigned short* Wgu = (unsigned short*)(ws + OFF_WGU);
    unsigned short* Wdb = (unsigned short*)(ws + OFF_WD);
    float* partial = (float*)(ws + OFF_WGU);  // 64 MB, aliases Wgu (dead after g1)

    hipMemsetAsync(ws, 0, 256, stream);

    router_kernel  <<<Tt, 64, 0, stream>>>(x, Wr, ids, wts, counts, xb);
    scan_kernel    <<<1, 64, 0, stream>>>(counts, cursor, eoff);
    scatter_kernel <<<Tt / 256, 256, 0, stream>>>(ids, cursor, rows);

    cvt_wgu        <<<32768, 256, 0, stream>>>(Wg, Wu, Wgu);

    g1_moe <<<dim3(2 * Ff / 256, Tt / 256, Ee), 512, 0, stream>>>(
        xb, Wgu, eoff, rows, H, Wd, Wdb);
    // g2: MT=320 -> my in 0..4 (early-exit beyond ceil(ne/320)); sK in {0,1}
    g2_moe <<<dim3(Dd / 256, 2 * 5, Ee), 512, 0, stream>>>(
        H, Wdb, eoff, rows, partial);

    reduce_kernel  <<<(Tt * Dd / 4) / 256, 256, 0, stream>>>(partial, wts, out);
}

// Round 13
// 494.757 us; speedup vs baseline: 1.1592x; 1.1592x over previous
//
#include <hip/hip_runtime.h>
#include <hip/hip_bf16.h>

// Problem constants
#define Tt 4096   // B*L tokens
#define Dd 1024   // model dim
#define Ee 8      // experts
#define Kk 2      // top-k
#define Ff 4096   // DFF

using f32x4  = __attribute__((ext_vector_type(4))) float;
using bf16x8 = __attribute__((ext_vector_type(8))) short;

__device__ __forceinline__ unsigned short f2bf(float f) {
    union { float fp; unsigned int u; } v; v.fp = f;
    unsigned int u = v.u;
    return (unsigned short)((u + 0x7FFFu + ((u >> 16) & 1u)) >> 16);  // RNE
}

__device__ __forceinline__ void gl16(const void* g, void* l) {
    __builtin_amdgcn_global_load_lds(
        (const __attribute__((address_space(1))) void*)g,
        (__attribute__((address_space(3))) void*)l, 16, 0, 0);
}

// ---------------- Router (+ x->bf16): logits fp64, softmax, top-2, renorm ----------------
__global__ void router_kernel(const float* __restrict__ x, const float* __restrict__ Wr,
                              int* __restrict__ ids, float* __restrict__ wts,
                              int* __restrict__ counts, unsigned short* __restrict__ xb) {
    const int t = blockIdx.x;
    const int lane = threadIdx.x;  // 64
    const float* xr = x + (size_t)t * Dd + lane * 16;
    float xv[16];
#pragma unroll
    for (int i = 0; i < 4; ++i) *(float4*)(xv + 4 * i) = *(const float4*)(xr + 4 * i);
    uint4 o0, o1;
    o0.x = (unsigned)f2bf(xv[0])  | ((unsigned)f2bf(xv[1])  << 16);
    o0.y = (unsigned)f2bf(xv[2])  | ((unsigned)f2bf(xv[3])  << 16);
    o0.z = (unsigned)f2bf(xv[4])  | ((unsigned)f2bf(xv[5])  << 16);
    o0.w = (unsigned)f2bf(xv[6])  | ((unsigned)f2bf(xv[7])  << 16);
    o1.x = (unsigned)f2bf(xv[8])  | ((unsigned)f2bf(xv[9])  << 16);
    o1.y = (unsigned)f2bf(xv[10]) | ((unsigned)f2bf(xv[11]) << 16);
    o1.z = (unsigned)f2bf(xv[12]) | ((unsigned)f2bf(xv[13]) << 16);
    o1.w = (unsigned)f2bf(xv[14]) | ((unsigned)f2bf(xv[15]) << 16);
    unsigned short* xo = xb + (size_t)t * Dd + lane * 16;
    *(uint4*)(xo) = o0;
    *(uint4*)(xo + 8) = o1;

    double dot[Ee];
#pragma unroll
    for (int e = 0; e < Ee; ++e) {
        const float* wr = Wr + e * Dd + lane * 16;
        double s = 0.0;
#pragma unroll
        for (int i = 0; i < 16; ++i) s += (double)xv[i] * (double)wr[i];
        dot[e] = s;
    }
#pragma unroll
    for (int off = 32; off >= 1; off >>= 1) {
#pragma unroll
        for (int e = 0; e < Ee; ++e) dot[e] += __shfl_xor(dot[e], off, 64);
    }
    if (lane == 0) {
        float lg[Ee];
#pragma unroll
        for (int e = 0; e < Ee; ++e) lg[e] = (float)dot[e];
        float m = lg[0];
        for (int e = 1; e < Ee; ++e) m = fmaxf(m, lg[e]);
        float ex[Ee]; float sum = 0.f;
        for (int e = 0; e < Ee; ++e) { ex[e] = expf(lg[e] - m); sum += ex[e]; }
        float s0 = -1.f, s1 = -1.f; int i0 = 0, i1 = 0;
        for (int e = 0; e < Ee; ++e) {
            float s = ex[e];
            if (s > s0)      { s1 = s0; i1 = i0; s0 = s; i0 = e; }
            else if (s > s1) { s1 = s; i1 = e; }
        }
        float inv = 1.f / sum;
        float sc0 = s0 * inv, sc1 = s1 * inv;
        float den = sc0 + sc1 + 1.1920929e-7f;
        ids[2 * t] = i0; ids[2 * t + 1] = i1;
        wts[2 * t] = sc0 / den; wts[2 * t + 1] = sc1 / den;
        atomicAdd(&counts[i0], 1);
        atomicAdd(&counts[i1], 1);
    }
}

// ---------------- Wg/Wu -> interleaved bf16 Wgu ----------------
__global__ void cvt_wgu(const float* __restrict__ Wg, const float* __restrict__ Wu,
                        unsigned short* __restrict__ Wgu) {
    size_t tid = (size_t)blockIdx.x * blockDim.x + threadIdx.x;
    size_t row = tid >> 7;          // 128 threads per 1024-elem row
    int dc  = (int)(tid & 127);
    int e   = (int)(row >> 13);     // 8192 rows/expert
    int j   = (int)(row & 8191);
    int fg = j >> 5, s = (j >> 4) & 1, fi = j & 15;
    int f  = fg * 16 + fi;
    const float* src = (s ? Wu : Wg) + ((size_t)e * Ff + f) * Dd + dc * 8;
    float4 a = *(const float4*)(src);
    float4 b = *(const float4*)(src + 4);
    uint4 o;
    o.x = (unsigned)f2bf(a.x) | ((unsigned)f2bf(a.y) << 16);
    o.y = (unsigned)f2bf(a.z) | ((unsigned)f2bf(a.w) << 16);
    o.z = (unsigned)f2bf(b.x) | ((unsigned)f2bf(b.y) << 16);
    o.w = (unsigned)f2bf(b.z) | ((unsigned)f2bf(b.w) << 16);
    *(uint4*)(Wgu + row * Dd + dc * 8) = o;
}

// ---------------- counts -> offsets + cursors ----------------
__global__ void scan_kernel(const int* __restrict__ counts, int* __restrict__ cursor,
                            int* __restrict__ eoff) {
    if (threadIdx.x == 0) {
        int acc = 0;
        for (int e = 0; e < Ee; ++e) { eoff[e] = acc; cursor[e] = acc; acc += counts[e]; }
        eoff[Ee] = acc;
    }
}

// ---------------- scatter: rows[pos] = 2*t+k ----------------
__global__ void scatter_kernel(const int* __restrict__ ids,
                               int* __restrict__ cursor, int* __restrict__ rows) {
    int t = blockIdx.x * blockDim.x + threadIdx.x;
    if (t >= Tt) return;
#pragma unroll
    for (int k = 0; k < Kk; ++k) {
        int e = ids[2 * t + k];
        int pos = atomicAdd(&cursor[e], 1);
        rows[pos] = 2 * t + k;
    }
}

// =================== MTx256 BK=64 8-wave 4-phase counted-vmcnt GEMM body ===================
// Schedule structure identical to round-6 (verified deterministic).
// G1: MT=256, MFR=8, AISS=4, steady vmcnt(4)  (r11 config, proven).
// G2: MT=128, MFR=4 (acc=64 VGPR, no spill -- r12 lesson), AISS=2, steady vmcnt(2);
//     split-K=2 -> active blocks = 4n x 2sK x ceil(ne/128)~8 x 8e ~ 512 ~ 2 rounds of
//     ~42us blocks per CU (kills r11's ~1.2-blocks/CU quantization at MT=256).
// Ledger (per r6 invariants): stages in tile t = B(t+1) [P1,P2] then A(t+2) [P3,P4];
// tile-end vmcnt(AISS) drains B(t+1), leaves A(t+2); tail vmcnt(0) once t+2>=NT;
// A-region WAR protected by end-P2 lgkm drain + barrier.

#define MFMA_BF16(a, b, c) __builtin_amdgcn_mfma_f32_16x16x32_bf16(a, b, c, 0, 0, 0)

template<bool G2>
__device__ __forceinline__ void gemm_body(unsigned short* Ls,
                                          const unsigned short* __restrict__ Abase,
                                          const unsigned short* __restrict__ Bbase,
                                          const int* __restrict__ eoff,
                                          const int* __restrict__ rows,
                                          unsigned short* __restrict__ H,
                                          float* __restrict__ partial) {
    constexpr int KLEN  = G2 ? Ff : Dd;            // physical A/B row length
    constexpr int NT    = (G2 ? 2048 : 1024) / 64; // K-tiles this block processes
    constexpr int MT    = G2 ? 128 : 256;          // M tile
    constexpr int MFR   = MT / 32;                 // m-frags per wave (4 / 8)
    constexpr int AISS  = MT / 64;                 // A gl16 issues per tile (2 / 4)
    constexpr int AH0   = AISS / 2;                // issues in half 0 (1 / 2)
    constexpr int ABUFU = MT * 64;                 // ushorts per A buffer
    constexpr int BBASE = 2 * ABUFU;               // B region offset (ushorts)
    const int e   = blockIdx.z;
    const int off = eoff[e];
    const int ne  = eoff[e + 1] - off;
    const int by  = blockIdx.y;
    const int my  = G2 ? (by >> 1) : by;
    const int sK  = G2 ? (by & 1) : 0;
    const int koff = sK * 2048;
    const int m0  = my * MT;
    if (m0 >= ne) return;
    const int n0  = blockIdx.x * 256;

    const int tid  = threadIdx.x;
    const int lane = tid & 63;
    const int w    = tid >> 6;        // wave 0..7
    const int wr   = w >> 2;          // 0..1 (M half)
    const int wc   = w & 3;           // 0..3 (N quarter)
    const int lr   = lane & 15;
    const int lc   = lane >> 4;       // 0..3

    const int sr = lane >> 3;                 // 0..7
    const int cA = (lane & 7) ^ sr;           // pre-swizzled source chunk
    int asrc[AISS];
#pragma unroll
    for (int j = 0; j < AISS; ++j) {
        int rr = m0 + j * 64 + w * 8 + sr;
        if (rr > ne - 1) rr = ne - 1;
        asrc[j] = (G2 ? (off + rr) : (rows[off + rr] >> 1)) * KLEN + cA * 8;
    }
    const unsigned short* Bp = Bbase + (size_t)e * (G2 ? (size_t)Dd * Ff : (size_t)8192 * Dd);
    int bsrc[4];
#pragma unroll
    for (int qq = 0; qq < 4; ++qq) {
        int rN = n0 + qq * 64 + w * 8 + sr;
        bsrc[qq] = rN * KLEN + cA * 8;
    }

    auto STAGE_A = [&](int T, int half) {
        const int bo_ = (T & 1) * ABUFU; const int kt_ = koff + T * 64;
        if (half == 0) {
#pragma unroll
            for (int j = 0; j < AH0; ++j)
                gl16(Abase + asrc[j] + kt_, Ls + bo_ + j * 4096 + w * 512);
        } else {
#pragma unroll
            for (int j = AH0; j < AISS; ++j)
                gl16(Abase + asrc[j] + kt_, Ls + bo_ + j * 4096 + w * 512);
        }
    };
    auto STAGE_B = [&](int T, int Hh) {
        const int bo_ = BBASE + (T & 1) * 16384; const int kt_ = koff + T * 64;
        gl16(Bp + bsrc[2 * Hh]     + kt_, Ls + bo_ + (2 * Hh)     * 4096 + w * 512);
        gl16(Bp + bsrc[2 * Hh + 1] + kt_, Ls + bo_ + (2 * Hh + 1) * 4096 + w * 512);
    };

#define WAIT_STEADY() do { if constexpr (G2) { asm volatile("s_waitcnt vmcnt(2)" ::: "memory"); } \
                           else              { asm volatile("s_waitcnt vmcnt(4)" ::: "memory"); } } while (0)

    const int ccx0 = ((0 * 4 + lc) ^ (lr & 7)) * 8;
    const int ccx1 = ((1 * 4 + lc) ^ (lr & 7)) * 8;
    const int aB = (wr * (MT / 2)) * 64 + lr * 64;     // + (t&1)*ABUFU + m*1024 + ccx
    const int bB = BBASE + wc * 4096 + lr * 64;        // + (t&1)*16384 + n*1024 + ccx

    f32x4 acc[MFR][4];
#pragma unroll
    for (int m = 0; m < MFR; ++m)
#pragma unroll
        for (int n = 0; n < 4; ++n) acc[m][n] = (f32x4){0.f, 0.f, 0.f, 0.f};

    // --- prologue: tile0 fully + tile1 A; wait leaves A(1) (AISS loads) in flight ---
    STAGE_A(0, 0); STAGE_A(0, 1); STAGE_B(0, 0); STAGE_B(0, 1);
    STAGE_A(1, 0); STAGE_A(1, 1);
    WAIT_STEADY();
    __builtin_amdgcn_sched_barrier(0);
    __builtin_amdgcn_s_barrier();

    bf16x8 a0[MFR], a1[MFR], b0[4], b1[4];

    for (int t = 0; t < NT; ++t) {
        const int abo = (t & 1) * ABUFU;
        const int bbo = (t & 1) * 16384;
        // ---- P1: read a_kk0 + b_kk0; stage (t+1).B0 ----
#pragma unroll
        for (int m = 0; m < MFR; ++m) a0[m] = *(const bf16x8*)(Ls + abo + aB + m * 1024 + ccx0);
#pragma unroll
        for (int n = 0; n < 4; ++n) b0[n] = *(const bf16x8*)(Ls + bbo + bB + n * 1024 + ccx0);
        if (t + 1 < NT) STAGE_B(t + 1, 0);
        __builtin_amdgcn_s_barrier();
        asm volatile("s_waitcnt lgkmcnt(0)" ::: "memory");
        __builtin_amdgcn_sched_barrier(0);
        __builtin_amdgcn_s_setprio(1);
#pragma unroll
        for (int m = 0; m < MFR; ++m) {
            acc[m][0] = MFMA_BF16(a0[m], b0[0], acc[m][0]);
            acc[m][1] = MFMA_BF16(a0[m], b0[1], acc[m][1]);
        }
        __builtin_amdgcn_s_setprio(0);
        __builtin_amdgcn_s_barrier();
        // ---- P2: read a_kk1; stage (t+1).B1; MFMA kk0 nh1; REQUIRED lgkm-drain ----
#pragma unroll
        for (int m = 0; m < MFR; ++m) a1[m] = *(const bf16x8*)(Ls + abo + aB + m * 1024 + ccx1);
        if (t + 1 < NT) STAGE_B(t + 1, 1);
        __builtin_amdgcn_s_barrier();
        __builtin_amdgcn_s_setprio(1);
#pragma unroll
        for (int m = 0; m < MFR; ++m) {
            acc[m][2] = MFMA_BF16(a0[m], b0[2], acc[m][2]);
            acc[m][3] = MFMA_BF16(a0[m], b0[3], acc[m][3]);
        }
        __builtin_amdgcn_s_setprio(0);
        asm volatile("s_waitcnt lgkmcnt(0)" ::: "memory");
        __builtin_amdgcn_sched_barrier(0);
        __builtin_amdgcn_s_barrier();
        // ---- P3: read b_kk1; stage (t+2).A0; MFMA kk1 nh0 ----
#pragma unroll
        for (int n = 0; n < 4; ++n) b1[n] = *(const bf16x8*)(Ls + bbo + bB + n * 1024 + ccx1);
        if (t + 2 < NT) STAGE_A(t + 2, 0);
        __builtin_amdgcn_s_barrier();
        asm volatile("s_waitcnt lgkmcnt(0)" ::: "memory");
        __builtin_amdgcn_sched_barrier(0);
        __builtin_amdgcn_s_setprio(1);
#pragma unroll
        for (int m = 0; m < MFR; ++m) {
            acc[m][0] = MFMA_BF16(a1[m], b1[0], acc[m][0]);
            acc[m][1] = MFMA_BF16(a1[m], b1[1], acc[m][1]);
        }
        __builtin_amdgcn_s_setprio(0);
        __builtin_amdgcn_s_barrier();
        // ---- P4: stage (t+2).A1; MFMA kk1 nh1; counted vmcnt (tail-corrected) ----
        if (t + 2 < NT) STAGE_A(t + 2, 1);
        __builtin_amdgcn_s_setprio(1);
#pragma unroll
        for (int m = 0; m < MFR; ++m) {
            acc[m][2] = MFMA_BF16(a1[m], b1[2], acc[m][2]);
            acc[m][3] = MFMA_BF16(a1[m], b1[3], acc[m][3]);
        }
        __builtin_amdgcn_s_setprio(0);
        if (t + 2 < NT) { WAIT_STEADY(); }
        else            { asm volatile("s_waitcnt vmcnt(0)" ::: "memory"); }
        __builtin_amdgcn_sched_barrier(0);
        __builtin_amdgcn_s_barrier();
    }

    if constexpr (!G2) {
        const int fg16 = ((n0 + wc * 64) >> 5) * 16 + lr;
#pragma unroll
        for (int m = 0; m < MFR; ++m) {
            const int itok = m0 + wr * (MT / 2) + m * 16 + lc * 4;
#pragma unroll
            for (int r = 0; r < 4; ++r) {
                const int i = itok + r;
                if (i < ne) {
                    unsigned short* hp = H + (size_t)(off + i) * Ff;
#pragma unroll
                    for (int np = 0; np < 2; ++np) {
                        const float g = acc[m][2 * np][r];
                        const float u = acc[m][2 * np + 1][r];
                        hp[fg16 + np * 16] = f2bf(fmaxf(g, 0.f) * u);
                    }
                }
            }
        }
    } else {
        const int dbase = n0 + wc * 64;
#pragma unroll
        for (int m = 0; m < MFR; ++m) {
            const int ib = m0 + wr * (MT / 2) + m * 16 + lc * 4;
#pragma unroll
            for (int r = 0; r < 4; ++r) {
                const int i = ib + r;
                if (i < ne) {
                    const int tr = rows[off + i];  // 2t+k, token-determined target
                    float* op = partial + ((size_t)sK * 8192 + tr) * Dd + dbase + lr;
#pragma unroll
                    for (int n = 0; n < 4; ++n) op[n * 16] = acc[m][n][r];
                }
            }
        }
    }
#undef WAIT_STEADY
}

// g1: gemm1 + folded Wd fp32->bf16 conversion tail (every block, incl. early-exit ones)
__global__ __launch_bounds__(512, 1)
void g1_moe(const unsigned short* __restrict__ xb, const unsigned short* __restrict__ Wgu,
            const int* __restrict__ eoff, const int* __restrict__ rows,
            unsigned short* __restrict__ H,
            const float* __restrict__ Wd, unsigned short* __restrict__ Wdb) {
    __shared__ __align__(16) unsigned short Ls[65536];  // 128 KiB
    gemm_body<false>(Ls, xb, Wgu, eoff, rows, H, nullptr);
    // Wd convert slice: 4096 blocks x 8192 elems = 33.55M
    const int fb = blockIdx.x + gridDim.x * (blockIdx.y + gridDim.y * blockIdx.z);
    const size_t base = (size_t)fb * 8192;
#pragma unroll
    for (int it = 0; it < 2; ++it) {
        const size_t i = base + (size_t)it * 4096 + threadIdx.x * 8;
        float4 a = *(const float4*)(Wd + i);
        float4 b = *(const float4*)(Wd + i + 4);
        uint4 o;
        o.x = (unsigned)f2bf(a.x) | ((unsigned)f2bf(a.y) << 16);
        o.y = (unsigned)f2bf(a.z) | ((unsigned)f2bf(a.w) << 16);
        o.z = (unsigned)f2bf(b.x) | ((unsigned)f2bf(b.y) << 16);
        o.w = (unsigned)f2bf(b.z) | ((unsigned)f2bf(b.w) << 16);
        *(uint4*)(Wdb + i) = o;
    }
}

__global__ __launch_bounds__(512, 1)
void g2_moe(const unsigned short* __restrict__ H, const unsigned short* __restrict__ Wdb,
            const int* __restrict__ eoff, const int* __restrict__ rows,
            float* __restrict__ partial) {
    __shared__ __align__(16) unsigned short Ls[49152];  // 96 KiB (2x8K A + 2x16K B ushorts)
    gemm_body<true>(Ls, H, Wdb, eoff, rows, nullptr, partial);
}

// ---------------- deterministic combine: out = w0*(P0a+P1a) + w1*(P0b+P1b) ----------------
__global__ void reduce_kernel(const float* __restrict__ P, const float* __restrict__ wts,
                              float* __restrict__ out) {
    const size_t idx = (size_t)blockIdx.x * blockDim.x + threadIdx.x;
    const size_t t  = idx >> 8;
    const int   dq  = (int)(idx & 255);
    const float w0 = wts[2 * t], w1 = wts[2 * t + 1];
    const float4* p00 = (const float4*)(P + (2 * t)        * Dd) + dq;
    const float4* p01 = (const float4*)(P + (2 * t + 1)    * Dd) + dq;
    const float4* p10 = (const float4*)(P + ((size_t)8192 + 2 * t)     * Dd) + dq;
    const float4* p11 = (const float4*)(P + ((size_t)8192 + 2 * t + 1) * Dd) + dq;
    float4 a = *p00, b = *p01, c = *p10, d = *p11;
    float4 o;
    o.x = w0 * (a.x + c.x) + w1 * (b.x + d.x);
    o.y = w0 * (a.y + c.y) + w1 * (b.y + d.y);
    o.z = w0 * (a.z + c.z) + w1 * (b.z + d.z);
    o.w = w0 * (a.w + c.w) + w1 * (b.w + d.w);
    ((float4*)(out + t * Dd))[dq] = o;
}

extern "C" void kernel_launch(void* const* d_in, const int* in_sizes, int n_in,
                              void* d_out, int out_size, void* d_ws, size_t ws_size,
                              hipStream_t stream) {
    const float* x  = (const float*)d_in[0];
    const float* Wr = (const float*)d_in[1];
    const float* Wg = (const float*)d_in[2];
    const float* Wu = (const float*)d_in[3];
    const float* Wd = (const float*)d_in[4];
    float* out = (float*)d_out;
    char* ws = (char*)d_ws;

    const size_t WELEM    = (size_t)Ee * Ff * Dd;            // 33.55M
    const size_t OFF_IDS  = 256;
    const size_t OFF_WTS  = OFF_IDS  + (size_t)Tt * 2 * 4;
    const size_t OFF_ROWS = OFF_WTS  + (size_t)Tt * 2 * 4;
    const size_t OFF_ROWW = OFF_ROWS + (size_t)Tt * Kk * 4;
    const size_t OFF_XB   = OFF_ROWW + (size_t)Tt * Kk * 4;
    const size_t OFF_H    = OFF_XB   + (size_t)Tt * Dd * 2;
    const size_t OFF_WGU  = OFF_H    + (size_t)Tt * Kk * Ff * 2;
    const size_t OFF_WD   = OFF_WGU  + WELEM * 2 * 2;        // Wgu = 2*WELEM bf16
    const size_t NEED     = OFF_WD   + WELEM * 2;            // ~264 MiB
    if (ws_size < NEED) return;

    int* counts = (int*)ws;
    int* cursor = (int*)(ws + 32);
    int* eoff   = (int*)(ws + 64);
    int* ids    = (int*)(ws + OFF_IDS);
    float* wts  = (float*)(ws + OFF_WTS);
    int* rows   = (int*)(ws + OFF_ROWS);
    unsigned short* xb  = (unsigned short*)(ws + OFF_XB);
    unsigned short* H   = (unsigned short*)(ws + OFF_H);
    unsigned short* Wgu = (unsigned short*)(ws + OFF_WGU);
    unsigned short* Wdb = (unsigned short*)(ws + OFF_WD);
    float* partial = (float*)(ws + OFF_WGU);  // 64 MB, aliases Wgu (dead after g1)

    hipMemsetAsync(ws, 0, 256, stream);

    router_kernel  <<<Tt, 64, 0, stream>>>(x, Wr, ids, wts, counts, xb);
    scan_kernel    <<<1, 64, 0, stream>>>(counts, cursor, eoff);
    scatter_kernel <<<Tt / 256, 256, 0, stream>>>(ids, cursor, rows);

    cvt_wgu        <<<32768, 256, 0, stream>>>(Wg, Wu, Wgu);

    g1_moe <<<dim3(2 * Ff / 256, Tt / 256, Ee), 512, 0, stream>>>(
        xb, Wgu, eoff, rows, H, Wd, Wdb);
    // g2: MT=128, split-K=2 -> y = 2 * 10 (my 0..9 covers ne<=1280; early-exit beyond)
    g2_moe <<<dim3(Dd / 256, 20, Ee), 512, 0, stream>>>(
        H, Wdb, eoff, rows, partial);

    reduce_kernel  <<<(Tt * Dd / 4) / 256, 256, 0, stream>>>(partial, wts, out);
}